// Round 1
// 599.016 us; speedup vs baseline: 1.0294x; 1.0294x over previous
//
#include <hip/hip_runtime.h>
#include <hip/hip_bf16.h>
#include <math.h>

#define D_MODEL 1024
#define INTER   1024
#define NEXP    8
#define T_TOK   8192
#define ROWCAP  17408   // 2*T + 8*127 padded up to 128

typedef short  short8 __attribute__((ext_vector_type(8)));
typedef float  f32x4  __attribute__((ext_vector_type(4)));

__device__ __forceinline__ ushort f2bf(float f) {
    uint u = __float_as_uint(f);
    u += 0x7fffu + ((u >> 16) & 1u);      // RNE (inputs finite)
    return (ushort)(u >> 16);
}
__device__ __forceinline__ float bf2f(ushort u) {
    return __uint_as_float((uint)u << 16);
}
__device__ __forceinline__ uint pk2(float lo, float hi) {
    return (uint)f2bf(lo) | ((uint)f2bf(hi) << 16);
}
__device__ __forceinline__ void gll16(const ushort* g, ushort* l) {
    __builtin_amdgcn_global_load_lds(
        (const __attribute__((address_space(1))) unsigned int*)(g),
        (__attribute__((address_space(3))) unsigned int*)(l), 16, 0, 0);
}

// tiled-swizzled LDS/weight image: 128 rows x 64 k bf16; row stride 64 ushort;
// logical 16B chunk c (0..7) of row r sits at image chunk c ^ (r & 7).
#define IDX64(r, c) ((r) * 64 + (((c) ^ ((r) & 7)) * 8))

// ---------------- gate: GW in regs, 8 tokens/wave, butterfly reduce --------
__global__ __launch_bounds__(256)
void k_gate(const float* __restrict__ X, const float* __restrict__ GW,
            int* __restrict__ topk_idx, float* __restrict__ topk_w,
            int* __restrict__ cnt)
{
    __shared__ int lcnt[NEXP];
    const int t = threadIdx.x;
    if (t < NEXP) lcnt[t] = 0;
    const int lane = t & 63, wv = t >> 6;
    float4 gwr[NEXP][4];
#pragma unroll
    for (int e = 0; e < NEXP; ++e)
#pragma unroll
        for (int i = 0; i < 4; ++i)
            gwr[e][i] = *(const float4*)(GW + e * 1024 + i * 256 + lane * 4);
    __syncthreads();
    const int tok0 = blockIdx.x * 32 + wv * 8;
    const bool b0 = lane & 1, b1 = lane & 2, b2 = lane & 4;
    for (int tt = 0; tt < 8; ++tt) {
        const int tok = tok0 + tt;
        const float* xr = X + (size_t)tok * 1024;
        float4 xv[4];
#pragma unroll
        for (int i = 0; i < 4; ++i) xv[i] = *(const float4*)(xr + i * 256 + lane * 4);
        float p[NEXP];
#pragma unroll
        for (int e = 0; e < NEXP; ++e) {
            float s = 0.f;
#pragma unroll
            for (int i = 0; i < 4; ++i)
                s += xv[i].x * gwr[e][i].x + xv[i].y * gwr[e][i].y
                   + xv[i].z * gwr[e][i].z + xv[i].w * gwr[e][i].w;
            p[e] = s;
        }
        float q[4];
#pragma unroll
        for (int j = 0; j < 4; ++j) {
            float send = b0 ? p[j] : p[j + 4];
            float recv = __shfl_xor(send, 1, 64);
            q[j] = (b0 ? p[j + 4] : p[j]) + recv;
        }
        float u2[2];
#pragma unroll
        for (int j = 0; j < 2; ++j) {
            float send = b1 ? q[j] : q[j + 2];
            float recv = __shfl_xor(send, 2, 64);
            u2[j] = (b1 ? q[j + 2] : q[j]) + recv;
        }
        float send = b2 ? u2[0] : u2[1];
        float r = (b2 ? u2[1] : u2[0]) + __shfl_xor(send, 4, 64);
        r += __shfl_xor(r, 8, 64);
        r += __shfl_xor(r, 16, 64);
        r += __shfl_xor(r, 32, 64);
        float sc[NEXP];
#pragma unroll
        for (int e = 0; e < NEXP; ++e)
            sc[e] = __shfl(r, ((e & 1) << 2) | (e & 2) | ((e >> 2) & 1), 64);
        float m = sc[0];
#pragma unroll
        for (int e = 1; e < NEXP; ++e) m = fmaxf(m, sc[e]);
        float ssum = 0.f;
#pragma unroll
        for (int e = 0; e < NEXP; ++e) { sc[e] = __expf(sc[e] - m); ssum += sc[e]; }
        float inv = 1.f / ssum;
#pragma unroll
        for (int e = 0; e < NEXP; ++e) sc[e] *= inv;
        int i0 = 0; float v0 = sc[0];
#pragma unroll
        for (int e = 1; e < NEXP; ++e) if (sc[e] > v0) { v0 = sc[e]; i0 = e; }
        int i1 = -1; float v1 = -1e30f;
#pragma unroll
        for (int e = 0; e < NEXP; ++e) if (e != i0 && sc[e] > v1) { v1 = sc[e]; i1 = e; }
        if (lane == 0) {
            topk_idx[2 * tok]     = i0;
            topk_idx[2 * tok + 1] = i1;
            topk_w[2 * tok]       = v0;
            topk_w[2 * tok + 1]   = v1;
            atomicAdd(&lcnt[i0], 1);
            atomicAdd(&lcnt[i1], 1);
        }
    }
    __syncthreads();
    if (t < NEXP) atomicAdd(&cnt[t], lcnt[t]);
}

__global__ void k_prefix(const int* __restrict__ cnt, int* __restrict__ offs)
{
    if (threadIdx.x == 0 && blockIdx.x == 0) {
        int tot = 0;
        for (int e = 0; e < NEXP; ++e) {
            offs[e] = tot;
            tot += ((cnt[e] + 127) / 128) * 128;
        }
        offs[NEXP] = tot;
    }
}

// scatter with block-aggregated atomics; also records which top-k slot (0/1)
__global__ void k_scatter(const int* __restrict__ topk_idx, const float* __restrict__ topk_w,
                          const int* __restrict__ offs, int* __restrict__ cnt2,
                          int* __restrict__ rowid, float* __restrict__ rowwt,
                          int* __restrict__ rowslot)
{
    __shared__ int loc[NEXP];
    __shared__ int base[NEXP];
    const int t = threadIdx.x;
    if (t < NEXP) loc[t] = 0;
    __syncthreads();
    const int tok = blockIdx.x * 256 + t;
    const int e0 = topk_idx[2 * tok], e1 = topk_idx[2 * tok + 1];
    const int s0 = atomicAdd(&loc[e0], 1);
    const int s1 = atomicAdd(&loc[e1], 1);
    __syncthreads();
    if (t < NEXP) base[t] = atomicAdd(&cnt2[t], loc[t]);
    __syncthreads();
    int p0 = offs[e0] + base[e0] + s0;
    rowid[p0] = tok; rowwt[p0] = topk_w[2 * tok]; rowslot[p0] = 0;
    int p1 = offs[e1] + base[e1] + s1;
    rowid[p1] = tok; rowwt[p1] = topk_w[2 * tok + 1]; rowslot[p1] = 1;
}

// ------- transpose fp32 [K][N] -> tiled swizzled bf16 (128n x 64k tiles) ----
__global__ __launch_bounds__(256)
void k_tw(const float* __restrict__ srcA, ushort* __restrict__ dstA,
          const float* __restrict__ srcB, ushort* __restrict__ dstB, int nA)
{
    __shared__ float tl[64][132];
    int m = blockIdx.y;
    const float* src; ushort* dst;
    if (m < nA) { src = srcA + ((size_t)m << 20); dst = dstA + ((size_t)m << 20); }
    else { m -= nA;  src = srcB + ((size_t)m << 20); dst = dstB + ((size_t)m << 20); }
    const int tile = blockIdx.x;            // nb*16 + kt
    const int nb = tile >> 4, kt = tile & 15;
    const int t = threadIdx.x;
    const int c4 = (t & 31) * 4, kr = t >> 5;
#pragma unroll
    for (int i = 0; i < 8; ++i) {
        const int kl = kr + 8 * i;
        float4 v = *(const float4*)(src + (size_t)(kt * 64 + kl) * 1024 + nb * 128 + c4);
        tl[kl][c4 + 0] = v.x; tl[kl][c4 + 1] = v.y;
        tl[kl][c4 + 2] = v.z; tl[kl][c4 + 3] = v.w;
    }
    __syncthreads();
    const int nl = t >> 1, h = t & 1;
    ushort* drow = dst + (size_t)tile * 8192 + nl * 64;
#pragma unroll
    for (int w = 0; w < 4; ++w) {
        const int cimg = h * 4 + w;
        const int cl = cimg ^ (nl & 7);
        float f[8];
#pragma unroll
        for (int j = 0; j < 8; ++j) f[j] = tl[cl * 8 + j][nl];
        uint4 o = { pk2(f[0], f[1]), pk2(f[2], f[3]), pk2(f[4], f[5]), pk2(f[6], f[7]) };
        *(uint4*)(drow + cimg * 8) = o;
    }
}

// ---------------- H = silu(X@W1+b1) * (X@W3+b3), BK=64, gll B-staging ------
template <bool ROUTED>
__global__ __launch_bounds__(256, 2)
void k_h(const float* __restrict__ X,
         const ushort* __restrict__ W1t, const float* __restrict__ B1,
         const ushort* __restrict__ W3t, const float* __restrict__ B3,
         ushort* __restrict__ Hb,
         const int* __restrict__ rowid, const int* __restrict__ offs,
         const int* __restrict__ cnt)
{
    __shared__ __align__(16) ushort As [128 * 64];
    __shared__ __align__(16) ushort B1s[128 * 64];
    __shared__ __align__(16) ushort B3s[128 * 64];

    const int nbx  = blockIdx.x;            // 0..7
    const int nb   = nbx * 128;
    const int row0 = blockIdx.y * 128;

    int rstart = 0, rcount = T_TOK;
    const ushort* w1 = W1t; const ushort* w3 = W3t;
    if constexpr (ROUTED) {
        const int total = offs[NEXP];
        if (row0 >= total) return;
        int e = 0;
        while (offs[e + 1] <= row0) ++e;
        rstart = offs[e]; rcount = cnt[e];
        w1 += (size_t)e << 20; B1 += e * INTER;
        w3 += (size_t)e << 20; B3 += e * INTER;
    }
    const int t = threadIdx.x;
    const ushort* g1 = w1 + (size_t)(nbx * 16) * 8192 + t * 8;
    const ushort* g3 = w3 + (size_t)(nbx * 16) * 8192 + t * 8;

    // A staging: row = t>>1, half = t&1 -> 32 fp32 -> 4 swizzled uint4
    const int arow = t >> 1, ah = t & 1;
    int atok;
    if constexpr (ROUTED) {
        bool valid = (row0 + arow - rstart) < rcount;
        atok = valid ? rowid[row0 + arow] : 0;
    } else {
        atok = row0 + arow;
    }
    const float* Ap = X + (size_t)atok * D_MODEL + ah * 32;
    int aoff[4];
#pragma unroll
    for (int w = 0; w < 4; ++w) aoff[w] = IDX64(arow, ah * 4 + w);

    // fragment offsets
    const int lane = t & 63, wid = t >> 6;
    const int wm = wid & 1, wn = wid >> 1;
    const int m16 = lane & 15, g = lane >> 4;
    int offA[2][4], offB[2][4];
#pragma unroll
    for (int ks = 0; ks < 2; ++ks)
#pragma unroll
        for (int i = 0; i < 4; ++i) {
            offA[ks][i] = IDX64(wm * 64 + i * 16 + m16, ks * 4 + g);
            offB[ks][i] = IDX64(wn * 64 + i * 16 + m16, ks * 4 + g);
        }

    const f32x4 zf = {0.f, 0.f, 0.f, 0.f};
    f32x4 acc1[4][4], acc3[4][4];
#pragma unroll
    for (int i = 0; i < 4; ++i)
#pragma unroll
        for (int j = 0; j < 4; ++j) { acc1[i][j] = zf; acc3[i][j] = zf; }

    for (int kt = 0; kt < 16; ++kt) {
        float4 av[8];
#pragma unroll
        for (int w = 0; w < 8; ++w) av[w] = *(const float4*)(Ap + kt * 64 + w * 4);
        __syncthreads();
#pragma unroll
        for (int c = 0; c < 4; ++c) {
            gll16(g1 + kt * 8192 + c * 2048, &B1s[c * 2048 + t * 8]);
            gll16(g3 + kt * 8192 + c * 2048, &B3s[c * 2048 + t * 8]);
        }
#pragma unroll
        for (int w = 0; w < 4; ++w) {
            uint4 aw = { pk2(av[2*w].x, av[2*w].y),     pk2(av[2*w].z, av[2*w].w),
                         pk2(av[2*w+1].x, av[2*w+1].y), pk2(av[2*w+1].z, av[2*w+1].w) };
            *(uint4*)&As[aoff[w]] = aw;
        }
        __syncthreads();   // drains vmcnt (gll) + lgkm
#pragma unroll
        for (int ks = 0; ks < 2; ++ks) {
            short8 af[4], b1f[4], b3f[4];
#pragma unroll
            for (int i = 0; i < 4; ++i) {
                af[i]  = *(const short8*)&As [offA[ks][i]];
                b1f[i] = *(const short8*)&B1s[offB[ks][i]];
                b3f[i] = *(const short8*)&B3s[offB[ks][i]];
            }
#pragma unroll
            for (int i = 0; i < 4; ++i)
#pragma unroll
                for (int j = 0; j < 4; ++j) {
                    acc1[i][j] = __builtin_amdgcn_mfma_f32_16x16x32_bf16(af[i], b1f[j], acc1[i][j], 0, 0, 0);
                    acc3[i][j] = __builtin_amdgcn_mfma_f32_16x16x32_bf16(af[i], b3f[j], acc3[i][j], 0, 0, 0);
                }
        }
    }

#pragma unroll
    for (int j = 0; j < 4; ++j) {
        const int gcol = nb + wn * 64 + j * 16 + m16;
        const float bb1 = B1[gcol];
        const float bb3 = B3[gcol];
#pragma unroll
        for (int i = 0; i < 4; ++i) {
            const int growb = row0 + wm * 64 + i * 16 + g * 4;
#pragma unroll
            for (int r = 0; r < 4; ++r) {
                float x1 = acc1[i][j][r] + bb1;
                float x3 = acc3[i][j][r] + bb3;
                float h = x1 / (1.f + __expf(-x1)) * x3;
                Hb[(size_t)(growb + r) * INTER + gcol] = f2bf(h);
            }
        }
    }
}

// ---------------- out epilogue modes:
//   MODE 0: shared expert  -> plain store to out
//   MODE 1: routed, atomic fallback (small workspace)
//   MODE 2: routed, race-free weighted bf16 store into Y[slot][tok][col]
template <int MODE>
__global__ __launch_bounds__(256, 2)
void k_out(const ushort* __restrict__ Hin,
           const ushort* __restrict__ W2t, const float* __restrict__ B2,
           float* __restrict__ out,
           const int* __restrict__ rowid, const int* __restrict__ offs,
           const int* __restrict__ cnt, const float* __restrict__ rowwt,
           const int* __restrict__ rowslot, ushort* __restrict__ Yb)
{
    __shared__ __align__(16) ushort As[128 * 64];
    __shared__ __align__(16) ushort Bs[128 * 64];

    const int nbx  = blockIdx.x;
    const int nb   = nbx * 128;
    const int row0 = blockIdx.y * 128;

    int rstart = 0, rcount = T_TOK;
    const ushort* w2 = W2t;
    if constexpr (MODE != 0) {
        const int total = offs[NEXP];
        if (row0 >= total) return;
        int e = 0;
        while (offs[e + 1] <= row0) ++e;
        rstart = offs[e]; rcount = cnt[e];
        w2 += (size_t)e << 20; B2 += e * D_MODEL;
    }
    const int t = threadIdx.x;
    const ushort* g2 = w2 + (size_t)(nbx * 16) * 8192 + t * 8;

    const int arow = t >> 1, ah = t & 1;
    const ushort* Ap = Hin + (size_t)(row0 + arow) * INTER + ah * 32;
    int aoff[4];
#pragma unroll
    for (int w = 0; w < 4; ++w) aoff[w] = IDX64(arow, ah * 4 + w);

    const int lane = t & 63, wid = t >> 6;
    const int wm = wid & 1, wn = wid >> 1;
    const int m16 = lane & 15, g = lane >> 4;
    int offA[2][4], offB[2][4];
#pragma unroll
    for (int ks = 0; ks < 2; ++ks)
#pragma unroll
        for (int i = 0; i < 4; ++i) {
            offA[ks][i] = IDX64(wm * 64 + i * 16 + m16, ks * 4 + g);
            offB[ks][i] = IDX64(wn * 64 + i * 16 + m16, ks * 4 + g);
        }

    const f32x4 zf = {0.f, 0.f, 0.f, 0.f};
    f32x4 acc[4][4];
#pragma unroll
    for (int i = 0; i < 4; ++i)
#pragma unroll
        for (int j = 0; j < 4; ++j) acc[i][j] = zf;

    for (int kt = 0; kt < 16; ++kt) {
        uint4 av[4];
#pragma unroll
        for (int w = 0; w < 4; ++w) av[w] = *(const uint4*)(Ap + kt * 64 + w * 8);
        __syncthreads();
#pragma unroll
        for (int c = 0; c < 4; ++c)
            gll16(g2 + kt * 8192 + c * 2048, &Bs[c * 2048 + t * 8]);
#pragma unroll
        for (int w = 0; w < 4; ++w)
            *(uint4*)&As[aoff[w]] = av[w];
        __syncthreads();
#pragma unroll
        for (int ks = 0; ks < 2; ++ks) {
            short8 af[4], bf[4];
#pragma unroll
            for (int i = 0; i < 4; ++i) {
                af[i] = *(const short8*)&As[offA[ks][i]];
                bf[i] = *(const short8*)&Bs[offB[ks][i]];
            }
#pragma unroll
            for (int i = 0; i < 4; ++i)
#pragma unroll
                for (int j = 0; j < 4; ++j)
                    acc[i][j] = __builtin_amdgcn_mfma_f32_16x16x32_bf16(af[i], bf[j], acc[i][j], 0, 0, 0);
        }
    }

#pragma unroll
    for (int i = 0; i < 4; ++i) {
#pragma unroll
        for (int r = 0; r < 4; ++r) {
            const int grow = row0 + wm * 64 + i * 16 + g * 4 + r;
            if constexpr (MODE == 0) {
#pragma unroll
                for (int j = 0; j < 4; ++j) {
                    const int gcol = nb + wn * 64 + j * 16 + m16;
                    out[(size_t)grow * D_MODEL + gcol] = acc[i][j][r] + B2[gcol];
                }
            } else {
                const bool valid = (grow - rstart) < rcount;
                if (!valid) continue;
                const int tok = rowid[grow];
                const float wt = rowwt[grow];
                if constexpr (MODE == 1) {
#pragma unroll
                    for (int j = 0; j < 4; ++j) {
                        const int gcol = nb + wn * 64 + j * 16 + m16;
                        atomicAdd(out + (size_t)tok * D_MODEL + gcol,
                                  wt * (acc[i][j][r] + B2[gcol]));
                    }
                } else {
                    const int sk = rowslot[grow];
                    ushort* yr = Yb + (((size_t)sk * T_TOK + tok) << 10);
#pragma unroll
                    for (int j = 0; j < 4; ++j) {
                        const int gcol = nb + wn * 64 + j * 16 + m16;
                        yr[gcol] = f2bf(wt * (acc[i][j][r] + B2[gcol]));
                    }
                }
            }
        }
    }
}

// ---------------- out[tok] += Y[0][tok] + Y[1][tok] (dense, coalesced) -----
__global__ __launch_bounds__(256)
void k_combine(float* __restrict__ out, const ushort* __restrict__ Yb)
{
    const int row = blockIdx.x;            // 0..8191
    const int c = threadIdx.x * 4;
    float4 o = *(const float4*)(out + (size_t)row * 1024 + c);
    ushort4 y0 = *(const ushort4*)(Yb + (size_t)row * 1024 + c);
    ushort4 y1 = *(const ushort4*)(Yb + ((size_t)(T_TOK + row)) * 1024 + c);
    o.x += bf2f(y0.x) + bf2f(y1.x);
    o.y += bf2f(y0.y) + bf2f(y1.y);
    o.z += bf2f(y0.z) + bf2f(y1.z);
    o.w += bf2f(y0.w) + bf2f(y1.w);
    *(float4*)(out + (size_t)row * 1024 + c) = o;
}

// ---------------- launcher ----------------
// ws map (bytes):
//   [0,32)        cnt        [64,96)   cnt2      [128,164) offs
//   [256,65792)   topk_idx   [65792,131328) topk_w
//   [131328,200960) rowid    [200960,270592) rowwt   [270592,340224) rowslot
//   [524288, 36175872)  Hb  (ROWCAP*2048 = 35.65 MB)
//   [36175872, 52953088) WA (16 MB)   [52953088, 69730304) WB (16 MB)
//   [69730304, 86507520) WC (16 MB, w2t when ws permits)
//   Y (routed k_out phase) = WA..WB, 32 MB = exactly 2*T_TOK*1024 bf16
extern "C" void kernel_launch(void* const* d_in, const int* in_sizes, int n_in,
                              void* d_out, int out_size, void* d_ws, size_t ws_size,
                              hipStream_t stream)
{
    const float* x   = (const float*)d_in[0];
    const float* gw  = (const float*)d_in[1];
    const float* w1  = (const float*)d_in[2];
    const float* b1  = (const float*)d_in[3];
    const float* w2  = (const float*)d_in[4];
    const float* b2  = (const float*)d_in[5];
    const float* w3  = (const float*)d_in[6];
    const float* b3  = (const float*)d_in[7];
    const float* sw1 = (const float*)d_in[8];
    const float* sb1 = (const float*)d_in[9];
    const float* sw2 = (const float*)d_in[10];
    const float* sb2 = (const float*)d_in[11];
    const float* sw3 = (const float*)d_in[12];
    const float* sb3 = (const float*)d_in[13];
    float* out = (float*)d_out;

    char* ws = (char*)d_ws;
    int*   cnt      = (int*)(ws);
    int*   cnt2     = (int*)(ws + 64);
    int*   offs     = (int*)(ws + 128);
    int*   topk_idx = (int*)(ws + 256);
    float* topk_w   = (float*)(ws + 256 + 65536);
    int*   rowid    = (int*)(ws + 256 + 131072);
    float* rowwt    = (float*)(ws + 256 + 131072 + ROWCAP * 4);
    int*   rowslot  = (int*)(ws + 256 + 131072 + ROWCAP * 8);
    ushort* Hb = (ushort*)(ws + 524288);
    ushort* WA = (ushort*)(ws + 524288 + (size_t)ROWCAP * 2048); // 36,175,872
    ushort* WB = WA + (8u << 20);                                // +16 MB
    ushort* WC = WB + (8u << 20);                                // +16 MB (optional)
    const bool bigws = ws_size >= (size_t)86507520;              // room for WC

    ushort* sw1t = WB;
    ushort* sw3t = WB + (1 << 20);
    ushort* sw2t = WA;
    ushort* w1t  = WA;
    ushort* w3t  = WB;
    ushort* w2t  = bigws ? WC : WA;
    ushort* Yb   = WA;   // 32 MB spanning WA+WB; w1t/w3t dead by routed k_out

    hipMemsetAsync(ws, 0, 256, stream);

    k_gate<<<256, 256, 0, stream>>>(x, gw, topk_idx, topk_w, cnt);
    k_prefix<<<1, 64, 0, stream>>>(cnt, offs);
    k_scatter<<<32, 256, 0, stream>>>(topk_idx, topk_w, offs, cnt2, rowid, rowwt, rowslot);

    // shared expert
    k_tw<<<dim3(128, 2), 256, 0, stream>>>(sw1, sw1t, sw3, sw3t, 1);
    k_h<false><<<dim3(8, 64), 256, 0, stream>>>(x, sw1t, sb1, sw3t, sb3, Hb,
                                                nullptr, nullptr, nullptr);
    k_tw<<<dim3(128, 1), 256, 0, stream>>>(sw2, sw2t, sw2, sw2t, 1);
    k_out<0><<<dim3(8, 64), 256, 0, stream>>>(Hb, sw2t, sb2, out,
                                              nullptr, nullptr, nullptr, nullptr,
                                              nullptr, nullptr);

    // routed experts
    k_tw<<<dim3(128, 16), 256, 0, stream>>>(w1, w1t, w3, w3t, 8);
    k_h<true><<<dim3(8, ROWCAP / 128), 256, 0, stream>>>(x, w1t, b1, w3t, b3, Hb,
                                                         rowid, offs, cnt);
    k_tw<<<dim3(128, 8), 256, 0, stream>>>(w2, w2t, w2, w2t, 8);
    if (bigws) {
        k_out<2><<<dim3(8, ROWCAP / 128), 256, 0, stream>>>(Hb, w2t, b2, out,
                                                            rowid, offs, cnt, rowwt,
                                                            rowslot, Yb);
        k_combine<<<T_TOK, 256, 0, stream>>>(out, Yb);
    } else {
        k_out<1><<<dim3(8, ROWCAP / 128), 256, 0, stream>>>(Hb, w2t, b2, out,
                                                            rowid, offs, cnt, rowwt,
                                                            rowslot, Yb);
    }
}

// Round 2
// 446.631 us; speedup vs baseline: 1.3806x; 1.3412x over previous
//
#include <hip/hip_runtime.h>
#include <hip/hip_bf16.h>
#include <math.h>

#define D_MODEL 1024
#define INTER   1024
#define NEXP    8
#define T_TOK   8192
#define ROWCAP  17408   // 2*T + 8*127 padded up to 128

typedef short  short8 __attribute__((ext_vector_type(8)));
typedef float  f32x4  __attribute__((ext_vector_type(4)));

__device__ __forceinline__ ushort f2bf(float f) {
    uint u = __float_as_uint(f);
    u += 0x7fffu + ((u >> 16) & 1u);      // RNE (inputs finite)
    return (ushort)(u >> 16);
}
__device__ __forceinline__ float bf2f(ushort u) {
    return __uint_as_float((uint)u << 16);
}
__device__ __forceinline__ uint pk2(float lo, float hi) {
    return (uint)f2bf(lo) | ((uint)f2bf(hi) << 16);
}
__device__ __forceinline__ void gll16(const ushort* g, ushort* l) {
    __builtin_amdgcn_global_load_lds(
        (const __attribute__((address_space(1))) unsigned int*)(g),
        (__attribute__((address_space(3))) unsigned int*)(l), 16, 0, 0);
}

// tiled-swizzled LDS/weight image: 128 rows x 64 k bf16; row stride 64 ushort;
// logical 16B chunk c (0..7) of row r sits at image chunk c ^ (r & 7).
#define IDX64(r, c) ((r) * 64 + (((c) ^ ((r) & 7)) * 8))

// ---------------- X fp32 -> bf16 (one-shot; enables gll16 A-staging) -------
__global__ __launch_bounds__(256)
void k_xbf(const float* __restrict__ X, ushort* __restrict__ Xb)
{
    const size_t i = ((size_t)blockIdx.x * 256 + threadIdx.x) * 8;
    float4 a = *(const float4*)(X + i);
    float4 b = *(const float4*)(X + i + 4);
    uint4 o = { pk2(a.x, a.y), pk2(a.z, a.w), pk2(b.x, b.y), pk2(b.z, b.w) };
    *(uint4*)(Xb + i) = o;
}

// ---------------- gate: GW in regs, 8 tokens/wave, butterfly reduce --------
__global__ __launch_bounds__(256)
void k_gate(const float* __restrict__ X, const float* __restrict__ GW,
            int* __restrict__ topk_idx, float* __restrict__ topk_w,
            int* __restrict__ cnt)
{
    __shared__ int lcnt[NEXP];
    const int t = threadIdx.x;
    if (t < NEXP) lcnt[t] = 0;
    const int lane = t & 63, wv = t >> 6;
    float4 gwr[NEXP][4];
#pragma unroll
    for (int e = 0; e < NEXP; ++e)
#pragma unroll
        for (int i = 0; i < 4; ++i)
            gwr[e][i] = *(const float4*)(GW + e * 1024 + i * 256 + lane * 4);
    __syncthreads();
    const int tok0 = blockIdx.x * 32 + wv * 8;
    const bool b0 = lane & 1, b1 = lane & 2, b2 = lane & 4;
    for (int tt = 0; tt < 8; ++tt) {
        const int tok = tok0 + tt;
        const float* xr = X + (size_t)tok * 1024;
        float4 xv[4];
#pragma unroll
        for (int i = 0; i < 4; ++i) xv[i] = *(const float4*)(xr + i * 256 + lane * 4);
        float p[NEXP];
#pragma unroll
        for (int e = 0; e < NEXP; ++e) {
            float s = 0.f;
#pragma unroll
            for (int i = 0; i < 4; ++i)
                s += xv[i].x * gwr[e][i].x + xv[i].y * gwr[e][i].y
                   + xv[i].z * gwr[e][i].z + xv[i].w * gwr[e][i].w;
            p[e] = s;
        }
        float q[4];
#pragma unroll
        for (int j = 0; j < 4; ++j) {
            float send = b0 ? p[j] : p[j + 4];
            float recv = __shfl_xor(send, 1, 64);
            q[j] = (b0 ? p[j + 4] : p[j]) + recv;
        }
        float u2[2];
#pragma unroll
        for (int j = 0; j < 2; ++j) {
            float send = b1 ? q[j] : q[j + 2];
            float recv = __shfl_xor(send, 2, 64);
            u2[j] = (b1 ? q[j + 2] : q[j]) + recv;
        }
        float send = b2 ? u2[0] : u2[1];
        float r = (b2 ? u2[1] : u2[0]) + __shfl_xor(send, 4, 64);
        r += __shfl_xor(r, 8, 64);
        r += __shfl_xor(r, 16, 64);
        r += __shfl_xor(r, 32, 64);
        float sc[NEXP];
#pragma unroll
        for (int e = 0; e < NEXP; ++e)
            sc[e] = __shfl(r, ((e & 1) << 2) | (e & 2) | ((e >> 2) & 1), 64);
        float m = sc[0];
#pragma unroll
        for (int e = 1; e < NEXP; ++e) m = fmaxf(m, sc[e]);
        float ssum = 0.f;
#pragma unroll
        for (int e = 0; e < NEXP; ++e) { sc[e] = __expf(sc[e] - m); ssum += sc[e]; }
        float inv = 1.f / ssum;
#pragma unroll
        for (int e = 0; e < NEXP; ++e) sc[e] *= inv;
        int i0 = 0; float v0 = sc[0];
#pragma unroll
        for (int e = 1; e < NEXP; ++e) if (sc[e] > v0) { v0 = sc[e]; i0 = e; }
        int i1 = -1; float v1 = -1e30f;
#pragma unroll
        for (int e = 0; e < NEXP; ++e) if (e != i0 && sc[e] > v1) { v1 = sc[e]; i1 = e; }
        if (lane == 0) {
            topk_idx[2 * tok]     = i0;
            topk_idx[2 * tok + 1] = i1;
            topk_w[2 * tok]       = v0;
            topk_w[2 * tok + 1]   = v1;
            atomicAdd(&lcnt[i0], 1);
            atomicAdd(&lcnt[i1], 1);
        }
    }
    __syncthreads();
    if (t < NEXP) atomicAdd(&cnt[t], lcnt[t]);
}

__global__ void k_prefix(const int* __restrict__ cnt, int* __restrict__ offs)
{
    if (threadIdx.x == 0 && blockIdx.x == 0) {
        int tot = 0;
        for (int e = 0; e < NEXP; ++e) {
            offs[e] = tot;
            tot += ((cnt[e] + 127) / 128) * 128;
        }
        offs[NEXP] = tot;
    }
}

// scatter with block-aggregated atomics; also records which top-k slot (0/1)
__global__ void k_scatter(const int* __restrict__ topk_idx, const float* __restrict__ topk_w,
                          const int* __restrict__ offs, int* __restrict__ cnt2,
                          int* __restrict__ rowid, float* __restrict__ rowwt,
                          int* __restrict__ rowslot)
{
    __shared__ int loc[NEXP];
    __shared__ int base[NEXP];
    const int t = threadIdx.x;
    if (t < NEXP) loc[t] = 0;
    __syncthreads();
    const int tok = blockIdx.x * 256 + t;
    const int e0 = topk_idx[2 * tok], e1 = topk_idx[2 * tok + 1];
    const int s0 = atomicAdd(&loc[e0], 1);
    const int s1 = atomicAdd(&loc[e1], 1);
    __syncthreads();
    if (t < NEXP) base[t] = atomicAdd(&cnt2[t], loc[t]);
    __syncthreads();
    int p0 = offs[e0] + base[e0] + s0;
    rowid[p0] = tok; rowwt[p0] = topk_w[2 * tok]; rowslot[p0] = 0;
    int p1 = offs[e1] + base[e1] + s1;
    rowid[p1] = tok; rowwt[p1] = topk_w[2 * tok + 1]; rowslot[p1] = 1;
}

// ------- transpose fp32 [K][N] -> tiled swizzled bf16 (128n x 64k tiles) ----
__global__ __launch_bounds__(256)
void k_tw(const float* __restrict__ srcA, ushort* __restrict__ dstA,
          const float* __restrict__ srcB, ushort* __restrict__ dstB, int nA)
{
    __shared__ float tl[64][132];
    int m = blockIdx.y;
    const float* src; ushort* dst;
    if (m < nA) { src = srcA + ((size_t)m << 20); dst = dstA + ((size_t)m << 20); }
    else { m -= nA;  src = srcB + ((size_t)m << 20); dst = dstB + ((size_t)m << 20); }
    const int tile = blockIdx.x;            // nb*16 + kt
    const int nb = tile >> 4, kt = tile & 15;
    const int t = threadIdx.x;
    const int c4 = (t & 31) * 4, kr = t >> 5;
#pragma unroll
    for (int i = 0; i < 8; ++i) {
        const int kl = kr + 8 * i;
        float4 v = *(const float4*)(src + (size_t)(kt * 64 + kl) * 1024 + nb * 128 + c4);
        tl[kl][c4 + 0] = v.x; tl[kl][c4 + 1] = v.y;
        tl[kl][c4 + 2] = v.z; tl[kl][c4 + 3] = v.w;
    }
    __syncthreads();
    const int nl = t >> 1, h = t & 1;
    ushort* drow = dst + (size_t)tile * 8192 + nl * 64;
#pragma unroll
    for (int w = 0; w < 4; ++w) {
        const int cimg = h * 4 + w;
        const int cl = cimg ^ (nl & 7);
        float f[8];
#pragma unroll
        for (int j = 0; j < 8; ++j) f[j] = tl[cl * 8 + j][nl];
        uint4 o = { pk2(f[0], f[1]), pk2(f[2], f[3]), pk2(f[4], f[5]), pk2(f[6], f[7]) };
        *(uint4*)(drow + cimg * 8) = o;
    }
}

// ---------------- H = silu(X@W1+b1) * (X@W3+b3), BK=64 --------------------
// AA=1: A-tile staged via gll16 from pre-converted bf16 X image (per-lane
//       inverse-swizzled global source, linear LDS dest). AA=0: legacy path.
template <bool ROUTED, bool AA>
__global__ __launch_bounds__(256, 2)
void k_h(const float* __restrict__ X, const ushort* __restrict__ Xb,
         const ushort* __restrict__ W1t, const float* __restrict__ B1,
         const ushort* __restrict__ W3t, const float* __restrict__ B3,
         ushort* __restrict__ Hb,
         const int* __restrict__ rowid, const int* __restrict__ offs,
         const int* __restrict__ cnt)
{
    __shared__ __align__(16) ushort As [128 * 64];
    __shared__ __align__(16) ushort B1s[128 * 64];
    __shared__ __align__(16) ushort B3s[128 * 64];
    __shared__ int ridc[128];

    const int nbx  = blockIdx.x;            // 0..7
    const int nb   = nbx * 128;
    const int row0 = blockIdx.y * 128;

    int rstart = 0, rcount = T_TOK;
    const ushort* w1 = W1t; const ushort* w3 = W3t;
    if constexpr (ROUTED) {
        const int total = offs[NEXP];
        if (row0 >= total) return;
        int e = 0;
        while (offs[e + 1] <= row0) ++e;
        rstart = offs[e]; rcount = cnt[e];
        w1 += (size_t)e << 20; B1 += e * INTER;
        w3 += (size_t)e << 20; B3 += e * INTER;
    }
    const int t = threadIdx.x;
    const ushort* g1 = w1 + (size_t)(nbx * 16) * 8192 + t * 8;
    const ushort* g3 = w3 + (size_t)(nbx * 16) * 8192 + t * 8;

    // ---- A staging setup ----
    const ushort* asrc[4];      // AA path: per-lane swizzled global sources
    const float*  Ap = nullptr; // legacy path
    int aoff[4];
    if constexpr (AA) {
        if constexpr (ROUTED) {
            if (t < 128) {
                const int rr = row0 + t;
                ridc[t] = ((rr - rstart) < rcount) ? rowid[rr] : 0;
            }
            __syncthreads();
        }
        const int sub = t >> 3, ci = t & 7;   // 8 threads cover one 128B row
#pragma unroll
        for (int c = 0; c < 4; ++c) {
            const int r = c * 32 + sub;
            const int tok = ROUTED ? ridc[r] : (row0 + r);
            asrc[c] = Xb + (size_t)tok * 1024 + (size_t)((ci ^ (sub & 7)) * 8);
        }
    } else {
        const int arow = t >> 1, ah = t & 1;
        int atok;
        if constexpr (ROUTED) {
            bool valid = (row0 + arow - rstart) < rcount;
            atok = valid ? rowid[row0 + arow] : 0;
        } else {
            atok = row0 + arow;
        }
        Ap = X + (size_t)atok * D_MODEL + ah * 32;
#pragma unroll
        for (int w = 0; w < 4; ++w) aoff[w] = IDX64(arow, ah * 4 + w);
    }

    // fragment offsets
    const int lane = t & 63, wid = t >> 6;
    const int wm = wid & 1, wn = wid >> 1;
    const int m16 = lane & 15, g = lane >> 4;
    int offA[2][4], offB[2][4];
#pragma unroll
    for (int ks = 0; ks < 2; ++ks)
#pragma unroll
        for (int i = 0; i < 4; ++i) {
            offA[ks][i] = IDX64(wm * 64 + i * 16 + m16, ks * 4 + g);
            offB[ks][i] = IDX64(wn * 64 + i * 16 + m16, ks * 4 + g);
        }

    const f32x4 zf = {0.f, 0.f, 0.f, 0.f};
    f32x4 acc1[4][4], acc3[4][4];
#pragma unroll
    for (int i = 0; i < 4; ++i)
#pragma unroll
        for (int j = 0; j < 4; ++j) { acc1[i][j] = zf; acc3[i][j] = zf; }

    for (int kt = 0; kt < 16; ++kt) {
        if constexpr (AA) {
            __syncthreads();   // previous MFMA done reading LDS
#pragma unroll
            for (int c = 0; c < 4; ++c)
                gll16(asrc[c] + kt * 64, &As[c * 2048 + t * 8]);
#pragma unroll
            for (int c = 0; c < 4; ++c) {
                gll16(g1 + kt * 8192 + c * 2048, &B1s[c * 2048 + t * 8]);
                gll16(g3 + kt * 8192 + c * 2048, &B3s[c * 2048 + t * 8]);
            }
            __syncthreads();   // drains vmcnt (gll)
        } else {
            float4 av[8];
#pragma unroll
            for (int w = 0; w < 8; ++w) av[w] = *(const float4*)(Ap + kt * 64 + w * 4);
            __syncthreads();
#pragma unroll
            for (int c = 0; c < 4; ++c) {
                gll16(g1 + kt * 8192 + c * 2048, &B1s[c * 2048 + t * 8]);
                gll16(g3 + kt * 8192 + c * 2048, &B3s[c * 2048 + t * 8]);
            }
#pragma unroll
            for (int w = 0; w < 4; ++w) {
                uint4 aw = { pk2(av[2*w].x, av[2*w].y),     pk2(av[2*w].z, av[2*w].w),
                             pk2(av[2*w+1].x, av[2*w+1].y), pk2(av[2*w+1].z, av[2*w+1].w) };
                *(uint4*)&As[aoff[w]] = aw;
            }
            __syncthreads();
        }
#pragma unroll
        for (int ks = 0; ks < 2; ++ks) {
            short8 af[4], b1f[4], b3f[4];
#pragma unroll
            for (int i = 0; i < 4; ++i) {
                af[i]  = *(const short8*)&As [offA[ks][i]];
                b1f[i] = *(const short8*)&B1s[offB[ks][i]];
                b3f[i] = *(const short8*)&B3s[offB[ks][i]];
            }
#pragma unroll
            for (int i = 0; i < 4; ++i)
#pragma unroll
                for (int j = 0; j < 4; ++j) {
                    acc1[i][j] = __builtin_amdgcn_mfma_f32_16x16x32_bf16(af[i], b1f[j], acc1[i][j], 0, 0, 0);
                    acc3[i][j] = __builtin_amdgcn_mfma_f32_16x16x32_bf16(af[i], b3f[j], acc3[i][j], 0, 0, 0);
                }
        }
    }

#pragma unroll
    for (int j = 0; j < 4; ++j) {
        const int gcol = nb + wn * 64 + j * 16 + m16;
        const float bb1 = B1[gcol];
        const float bb3 = B3[gcol];
#pragma unroll
        for (int i = 0; i < 4; ++i) {
            const int growb = row0 + wm * 64 + i * 16 + g * 4;
#pragma unroll
            for (int r = 0; r < 4; ++r) {
                float x1 = acc1[i][j][r] + bb1;
                float x3 = acc3[i][j][r] + bb3;
                float h = x1 / (1.f + __expf(-x1)) * x3;
                Hb[(size_t)(growb + r) * INTER + gcol] = f2bf(h);
            }
        }
    }
}

// ---------------- out epilogue modes:
//   MODE 0: shared expert  -> plain store to out
//   MODE 1: routed, atomic fallback (small workspace)
//   MODE 2: routed, race-free weighted bf16 store into Y[slot][tok][col]
// A-tile always staged via gll16 from bf16 Hin (linear rows, swizzled source).
template <int MODE>
__global__ __launch_bounds__(256, 2)
void k_out(const ushort* __restrict__ Hin,
           const ushort* __restrict__ W2t, const float* __restrict__ B2,
           float* __restrict__ out,
           const int* __restrict__ rowid, const int* __restrict__ offs,
           const int* __restrict__ cnt, const float* __restrict__ rowwt,
           const int* __restrict__ rowslot, ushort* __restrict__ Yb)
{
    __shared__ __align__(16) ushort As[128 * 64];
    __shared__ __align__(16) ushort Bs[128 * 64];

    const int nbx  = blockIdx.x;
    const int nb   = nbx * 128;
    const int row0 = blockIdx.y * 128;

    int rstart = 0, rcount = T_TOK;
    const ushort* w2 = W2t;
    if constexpr (MODE != 0) {
        const int total = offs[NEXP];
        if (row0 >= total) return;
        int e = 0;
        while (offs[e + 1] <= row0) ++e;
        rstart = offs[e]; rcount = cnt[e];
        w2 += (size_t)e << 20; B2 += e * D_MODEL;
    }
    const int t = threadIdx.x;
    const ushort* g2 = w2 + (size_t)(nbx * 16) * 8192 + t * 8;

    // A staging: per-lane inverse-swizzled source, linear LDS dest
    const int sub = t >> 3, ci = t & 7;
    const ushort* asrc[4];
#pragma unroll
    for (int c = 0; c < 4; ++c) {
        const int r = c * 32 + sub;
        asrc[c] = Hin + (size_t)(row0 + r) * 1024 + (size_t)((ci ^ (sub & 7)) * 8);
    }

    const int lane = t & 63, wid = t >> 6;
    const int wm = wid & 1, wn = wid >> 1;
    const int m16 = lane & 15, g = lane >> 4;
    int offA[2][4], offB[2][4];
#pragma unroll
    for (int ks = 0; ks < 2; ++ks)
#pragma unroll
        for (int i = 0; i < 4; ++i) {
            offA[ks][i] = IDX64(wm * 64 + i * 16 + m16, ks * 4 + g);
            offB[ks][i] = IDX64(wn * 64 + i * 16 + m16, ks * 4 + g);
        }

    const f32x4 zf = {0.f, 0.f, 0.f, 0.f};
    f32x4 acc[4][4];
#pragma unroll
    for (int i = 0; i < 4; ++i)
#pragma unroll
        for (int j = 0; j < 4; ++j) acc[i][j] = zf;

    for (int kt = 0; kt < 16; ++kt) {
        __syncthreads();
#pragma unroll
        for (int c = 0; c < 4; ++c)
            gll16(asrc[c] + kt * 64, &As[c * 2048 + t * 8]);
#pragma unroll
        for (int c = 0; c < 4; ++c)
            gll16(g2 + kt * 8192 + c * 2048, &Bs[c * 2048 + t * 8]);
        __syncthreads();
#pragma unroll
        for (int ks = 0; ks < 2; ++ks) {
            short8 af[4], bf[4];
#pragma unroll
            for (int i = 0; i < 4; ++i) {
                af[i] = *(const short8*)&As[offA[ks][i]];
                bf[i] = *(const short8*)&Bs[offB[ks][i]];
            }
#pragma unroll
            for (int i = 0; i < 4; ++i)
#pragma unroll
                for (int j = 0; j < 4; ++j)
                    acc[i][j] = __builtin_amdgcn_mfma_f32_16x16x32_bf16(af[i], bf[j], acc[i][j], 0, 0, 0);
        }
    }

#pragma unroll
    for (int i = 0; i < 4; ++i) {
#pragma unroll
        for (int r = 0; r < 4; ++r) {
            const int grow = row0 + wm * 64 + i * 16 + g * 4 + r;
            if constexpr (MODE == 0) {
#pragma unroll
                for (int j = 0; j < 4; ++j) {
                    const int gcol = nb + wn * 64 + j * 16 + m16;
                    out[(size_t)grow * D_MODEL + gcol] = acc[i][j][r] + B2[gcol];
                }
            } else {
                const bool valid = (grow - rstart) < rcount;
                if (!valid) continue;
                const int tok = rowid[grow];
                const float wt = rowwt[grow];
                if constexpr (MODE == 1) {
#pragma unroll
                    for (int j = 0; j < 4; ++j) {
                        const int gcol = nb + wn * 64 + j * 16 + m16;
                        atomicAdd(out + (size_t)tok * D_MODEL + gcol,
                                  wt * (acc[i][j][r] + B2[gcol]));
                    }
                } else {
                    const int sk = rowslot[grow];
                    ushort* yr = Yb + (((size_t)sk * T_TOK + tok) << 10);
#pragma unroll
                    for (int j = 0; j < 4; ++j) {
                        const int gcol = nb + wn * 64 + j * 16 + m16;
                        yr[gcol] = f2bf(wt * (acc[i][j][r] + B2[gcol]));
                    }
                }
            }
        }
    }
}

// ---------------- out[tok] += Y[0][tok] + Y[1][tok] (dense, coalesced) -----
__global__ __launch_bounds__(256)
void k_combine(float* __restrict__ out, const ushort* __restrict__ Yb)
{
    const int row = blockIdx.x;            // 0..8191
    const int c = threadIdx.x * 4;
    float4 o = *(const float4*)(out + (size_t)row * 1024 + c);
    ushort4 y0 = *(const ushort4*)(Yb + (size_t)row * 1024 + c);
    ushort4 y1 = *(const ushort4*)(Yb + ((size_t)(T_TOK + row)) * 1024 + c);
    o.x += bf2f(y0.x) + bf2f(y1.x);
    o.y += bf2f(y0.y) + bf2f(y1.y);
    o.z += bf2f(y0.z) + bf2f(y1.z);
    o.w += bf2f(y0.w) + bf2f(y1.w);
    *(float4*)(out + (size_t)row * 1024 + c) = o;
}

// ---------------- launcher ----------------
// ws map (bytes):
//   [0,32)        cnt        [64,96)   cnt2      [128,164) offs
//   [256,65792)   topk_idx   [65792,131328) topk_w
//   [131328,200960) rowid    [200960,270592) rowwt   [270592,340224) rowslot
//   [524288, 36175872)  Hb  (ROWCAP*2048 = 35.65 MB)
//   [36175872, 52953088) WA (16 MB)   [52953088, 69730304) WB (16 MB)
//   [69730304, 86507520) WC (16 MB): Xbf until routed k_h done, then w2t
//   Y (routed k_out phase) = WA..WB, 32 MB = exactly 2*T_TOK*1024 bf16
extern "C" void kernel_launch(void* const* d_in, const int* in_sizes, int n_in,
                              void* d_out, int out_size, void* d_ws, size_t ws_size,
                              hipStream_t stream)
{
    const float* x   = (const float*)d_in[0];
    const float* gw  = (const float*)d_in[1];
    const float* w1  = (const float*)d_in[2];
    const float* b1  = (const float*)d_in[3];
    const float* w2  = (const float*)d_in[4];
    const float* b2  = (const float*)d_in[5];
    const float* w3  = (const float*)d_in[6];
    const float* b3  = (const float*)d_in[7];
    const float* sw1 = (const float*)d_in[8];
    const float* sb1 = (const float*)d_in[9];
    const float* sw2 = (const float*)d_in[10];
    const float* sb2 = (const float*)d_in[11];
    const float* sw3 = (const float*)d_in[12];
    const float* sb3 = (const float*)d_in[13];
    float* out = (float*)d_out;

    char* ws = (char*)d_ws;
    int*   cnt      = (int*)(ws);
    int*   cnt2     = (int*)(ws + 64);
    int*   offs     = (int*)(ws + 128);
    int*   topk_idx = (int*)(ws + 256);
    float* topk_w   = (float*)(ws + 256 + 65536);
    int*   rowid    = (int*)(ws + 256 + 131072);
    float* rowwt    = (float*)(ws + 256 + 131072 + ROWCAP * 4);
    int*   rowslot  = (int*)(ws + 256 + 131072 + ROWCAP * 8);
    ushort* Hb = (ushort*)(ws + 524288);
    ushort* WA = (ushort*)(ws + 524288 + (size_t)ROWCAP * 2048); // 36,175,872
    ushort* WB = WA + (8u << 20);                                // +16 MB
    ushort* WC = WB + (8u << 20);                                // +16 MB (optional)
    const bool bigws = ws_size >= (size_t)86507520;              // room for WC

    ushort* sw1t = WB;
    ushort* sw3t = WB + (1 << 20);
    ushort* sw2t = WA;
    ushort* w1t  = WA;
    ushort* w3t  = WB;
    ushort* w2t  = bigws ? WC : WA;
    ushort* Xbf  = WC;   // alive until routed k_h done; then k_tw(w2) reuses WC
    ushort* Yb   = WA;   // 32 MB spanning WA+WB; w1t/w3t dead by routed k_out

    hipMemsetAsync(ws, 0, 256, stream);

    k_gate<<<256, 256, 0, stream>>>(x, gw, topk_idx, topk_w, cnt);
    k_prefix<<<1, 64, 0, stream>>>(cnt, offs);
    k_scatter<<<32, 256, 0, stream>>>(topk_idx, topk_w, offs, cnt2, rowid, rowwt, rowslot);

    if (bigws) {
        k_xbf<<<4096, 256, 0, stream>>>(x, Xbf);

        // shared expert
        k_tw<<<dim3(128, 2), 256, 0, stream>>>(sw1, sw1t, sw3, sw3t, 1);
        k_h<false, true><<<dim3(8, 64), 256, 0, stream>>>(x, Xbf, sw1t, sb1, sw3t, sb3, Hb,
                                                          nullptr, nullptr, nullptr);
        k_tw<<<dim3(128, 1), 256, 0, stream>>>(sw2, sw2t, sw2, sw2t, 1);
        k_out<0><<<dim3(8, 64), 256, 0, stream>>>(Hb, sw2t, sb2, out,
                                                  nullptr, nullptr, nullptr, nullptr,
                                                  nullptr, nullptr);

        // routed experts
        k_tw<<<dim3(128, 16), 256, 0, stream>>>(w1, w1t, w3, w3t, 8);
        k_h<true, true><<<dim3(8, ROWCAP / 128), 256, 0, stream>>>(x, Xbf, w1t, b1, w3t, b3, Hb,
                                                                   rowid, offs, cnt);
        k_tw<<<dim3(128, 8), 256, 0, stream>>>(w2, w2t, w2, w2t, 8);   // overwrites Xbf (dead)
        k_out<2><<<dim3(8, ROWCAP / 128), 256, 0, stream>>>(Hb, w2t, b2, out,
                                                            rowid, offs, cnt, rowwt,
                                                            rowslot, Yb);
        k_combine<<<T_TOK, 256, 0, stream>>>(out, Yb);
    } else {
        // small-workspace fallback: legacy reg-staged A, atomic k_out
        k_tw<<<dim3(128, 2), 256, 0, stream>>>(sw1, sw1t, sw3, sw3t, 1);
        k_h<false, false><<<dim3(8, 64), 256, 0, stream>>>(x, nullptr, sw1t, sb1, sw3t, sb3, Hb,
                                                           nullptr, nullptr, nullptr);
        k_tw<<<dim3(128, 1), 256, 0, stream>>>(sw2, sw2t, sw2, sw2t, 1);
        k_out<0><<<dim3(8, 64), 256, 0, stream>>>(Hb, sw2t, sb2, out,
                                                  nullptr, nullptr, nullptr, nullptr,
                                                  nullptr, nullptr);
        k_tw<<<dim3(128, 16), 256, 0, stream>>>(w1, w1t, w3, w3t, 8);
        k_h<true, false><<<dim3(8, ROWCAP / 128), 256, 0, stream>>>(x, nullptr, w1t, b1, w3t, b3, Hb,
                                                                    rowid, offs, cnt);
        k_tw<<<dim3(128, 8), 256, 0, stream>>>(w2, w2t, w2, w2t, 8);
        k_out<1><<<dim3(8, ROWCAP / 128), 256, 0, stream>>>(Hb, w2t, b2, out,
                                                            rowid, offs, cnt, rowwt,
                                                            rowslot, Yb);
    }
}